// Round 5
// baseline (192.442 us; speedup 1.0000x reference)
//
#include <hip/hip_runtime.h>
#include <math.h>

#define B_    4
#define L_    4096
#define DM    128
#define DI    256
#define DS    16
#define DTR   8
#define XPN   (DTR + 2*DS)   // 40
#define NB    (DI + 2*DS)    // 288 fused xproj output cols
#define M_    (B_*L_)        // 16384
#define CHUNK 32
#define NC    (L_/CHUNK)     // 128
#define LOG2E 1.4426950408889634f
#define PREP_N (512*128 + NB*DI + DM*DI)   // 172032

typedef __attribute__((ext_vector_type(8))) short bf16x8;   // 8 bf16 = 4 VGPR
typedef __attribute__((ext_vector_type(4))) float f32x4;    // MFMA acc
typedef unsigned short ushort_t;

__device__ __forceinline__ ushort_t f2bf(float f) {  // fp32 -> bf16 RNE
  unsigned int u = __float_as_uint(f);
  u += 0x7FFFu + ((u >> 16) & 1u);
  return (ushort_t)(u >> 16);
}

// ---------------- prep (weights->bf16 transposed, dtproj folded) + rmsnorm ----
__global__ __launch_bounds__(256) void prep_rms_kernel(const float* __restrict__ x,
                                                       const float* __restrict__ nw,
                                                       const float* __restrict__ inW,
                                                       const float* __restrict__ Wx,
                                                       const float* __restrict__ Wdt,
                                                       const float* __restrict__ outw,
                                                       ushort_t* __restrict__ xbf,
                                                       ushort_t* __restrict__ inWt,
                                                       ushort_t* __restrict__ WbigT,
                                                       ushort_t* __restrict__ outWt) {
  if (blockIdx.x < M_ / 4) {  // rmsnorm -> bf16
    int row  = blockIdx.x * 4 + (threadIdx.x >> 6);
    int lane = threadIdx.x & 63;
    const float* xp = x + (size_t)row * DM;
    float v0 = xp[lane], v1 = xp[lane + 64];
    float s = v0 * v0 + v1 * v1;
    #pragma unroll
    for (int off = 32; off > 0; off >>= 1) s += __shfl_xor(s, off);
    float r = rsqrtf(s / DM + 1e-5f);
    ushort_t* op = xbf + (size_t)row * DM;
    op[lane]      = f2bf(v0 * r * nw[lane]);
    op[lane + 64] = f2bf(v1 * r * nw[lane + 64]);
    return;
  }
  int g = (blockIdx.x - M_ / 4) * 256 + threadIdx.x;
  if (g < 512 * 128) {
    int n = g >> 7, k = g & 127;
    inWt[g] = f2bf(inW[k * 512 + n]);
  } else if (g < 512 * 128 + NB * DI) {
    int q = g - 512 * 128;
    int c = q >> 8, k = q & 255;
    float v;
    if (c < DI) {
      v = 0.f;
      #pragma unroll
      for (int j = 0; j < DTR; ++j) v = fmaf(Wx[k * XPN + j], Wdt[j * DI + c], v);
    } else {
      v = Wx[k * XPN + DTR + (c - DI)];
    }
    WbigT[q] = f2bf(v);
  } else if (g < PREP_N) {
    int q = g - (512 * 128 + NB * DI);
    int n = q >> 8, k = q & 255;
    outWt[q] = f2bf(outw[k * DM + n]);
  }
}

// ---------------- bf16 MFMA GEMM: C[M,N] = A[M,K] @ Wt[N,K]^T ---------------
// BM=128, BK=64, 4 waves; wave w: rows w*32..w*32+31, all BN cols.
// EPI 0: C fp32 (ldc).  EPI 1: xproj epilogue (delta/Bm/Cm).  EPI 2: C = acc + X.
template <int BN, int EPI>
__global__ __launch_bounds__(256) void gemm_mfma_kernel(const ushort_t* __restrict__ A,
                                                        const ushort_t* __restrict__ Wt,
                                                        float* __restrict__ C, int K, int ldc,
                                                        const float* __restrict__ bdt,
                                                        float* __restrict__ Bm,
                                                        float* __restrict__ Cm,
                                                        const float* __restrict__ X) {
  constexpr int BM = 128, BK = 64, NT = BN / 16;
  __shared__ __align__(16) ushort_t Asm[BK / 8][BM + 1][8];
  __shared__ __align__(16) ushort_t Bsm[BK / 8][BN + 1][8];
  const int tid  = threadIdx.x;
  const int wave = tid >> 6, lane = tid & 63;
  const int quad = lane >> 4, l16 = lane & 15;
  const int row0 = blockIdx.x * BM;
  const int col0 = blockIdx.y * BN;
  f32x4 acc[2][NT];
  #pragma unroll
  for (int mt = 0; mt < 2; ++mt)
    #pragma unroll
    for (int nt = 0; nt < NT; ++nt) acc[mt][nt] = (f32x4){0.f, 0.f, 0.f, 0.f};

  for (int k0 = 0; k0 < K; k0 += BK) {
    #pragma unroll
    for (int i = 0; i < 4; ++i) {  // A: 128x64 bf16 = 1024 b128
      int q = tid + i * 256;
      int m = q >> 3, kb = q & 7;
      *(bf16x8*)(&Asm[kb][m][0]) =
          *(const bf16x8*)(A + (size_t)(row0 + m) * K + k0 + kb * 8);
    }
    #pragma unroll
    for (int i = 0; i < (BN * 8) / 256; ++i) {  // B: BNx64 bf16
      int q = tid + i * 256;
      int n = q >> 3, kb = q & 7;
      *(bf16x8*)(&Bsm[kb][n][0]) =
          *(const bf16x8*)(Wt + (size_t)(col0 + n) * K + k0 + kb * 8);
    }
    __syncthreads();
    #pragma unroll
    for (int ks = 0; ks < 2; ++ks) {
      bf16x8 af[2], bfr[NT];
      #pragma unroll
      for (int mt = 0; mt < 2; ++mt)
        af[mt] = *(const bf16x8*)(&Asm[ks * 4 + quad][wave * 32 + mt * 16 + l16][0]);
      #pragma unroll
      for (int nt = 0; nt < NT; ++nt)
        bfr[nt] = *(const bf16x8*)(&Bsm[ks * 4 + quad][nt * 16 + l16][0]);
      #pragma unroll
      for (int mt = 0; mt < 2; ++mt)
        #pragma unroll
        for (int nt = 0; nt < NT; ++nt)
          acc[mt][nt] = __builtin_amdgcn_mfma_f32_16x16x32_bf16(af[mt], bfr[nt],
                                                                acc[mt][nt], 0, 0, 0);
    }
    __syncthreads();
  }
  #pragma unroll
  for (int mt = 0; mt < 2; ++mt) {
    #pragma unroll
    for (int nt = 0; nt < NT; ++nt) {
      int col   = col0 + nt * 16 + l16;
      int rbase = row0 + wave * 32 + mt * 16 + quad * 4;
      if (EPI == 0) {
        #pragma unroll
        for (int r = 0; r < 4; ++r)
          C[(size_t)(rbase + r) * ldc + col] = acc[mt][nt][r];
      } else if (EPI == 1) {
        if (col < DI) {
          float bb = bdt[col];
          #pragma unroll
          for (int r = 0; r < 4; ++r) {
            float v = acc[mt][nt][r] + bb;
            C[(size_t)(rbase + r) * DI + col] = (v > 20.f) ? v : log1pf(__expf(v));
          }
        } else if (col < DI + DS) {
          #pragma unroll
          for (int r = 0; r < 4; ++r)
            Bm[(size_t)(rbase + r) * DS + (col - DI)] = acc[mt][nt][r];
        } else {
          #pragma unroll
          for (int r = 0; r < 4; ++r)
            Cm[(size_t)(rbase + r) * DS + (col - DI - DS)] = acc[mt][nt][r];
        }
      } else {
        #pragma unroll
        for (int r = 0; r < 4; ++r)
          C[(size_t)(rbase + r) * ldc + col] =
              acc[mt][nt][r] + X[(size_t)(rbase + r) * ldc + col];
      }
    }
  }
}

// ---------------- conv1d (depthwise, causal, k=4) + SiLU, float4 -------------
__global__ __launch_bounds__(256) void conv_silu_kernel(const float* __restrict__ xr,
                                                        const float* __restrict__ cw,
                                                        const float* __restrict__ cb,
                                                        float* __restrict__ xc,
                                                        ushort_t* __restrict__ xcbf) {
  int idx4 = blockIdx.x * 256 + threadIdx.x;  // over M_*DI/4
  int d4 = idx4 & 63;
  int bl = idx4 >> 6;
  int l  = bl & (L_ - 1);
  int d  = d4 * 4;
  const float4* cw4 = (const float4*)(cw + d * 4);
  float4 w0 = cw4[0], w1 = cw4[1], w2 = cw4[2], w3 = cw4[3];  // taps for d..d+3
  float4 bias = *(const float4*)(cb + d);
  const float* base = xr + (size_t)bl * 512 + d;
  float4 z = make_float4(0.f, 0.f, 0.f, 0.f);
  float4 t0 = (l >= 3) ? *(const float4*)(base - 3 * 512) : z;
  float4 t1 = (l >= 2) ? *(const float4*)(base - 2 * 512) : z;
  float4 t2 = (l >= 1) ? *(const float4*)(base - 1 * 512) : z;
  float4 t3 = *(const float4*)(base);
  float4 s;
  s.x = fmaf(w0.x, t0.x, fmaf(w0.y, t1.x, fmaf(w0.z, t2.x, fmaf(w0.w, t3.x, bias.x))));
  s.y = fmaf(w1.x, t0.y, fmaf(w1.y, t1.y, fmaf(w1.z, t2.y, fmaf(w1.w, t3.y, bias.y))));
  s.z = fmaf(w2.x, t0.z, fmaf(w2.y, t1.z, fmaf(w2.z, t2.z, fmaf(w2.w, t3.z, bias.z))));
  s.w = fmaf(w3.x, t0.w, fmaf(w3.y, t1.w, fmaf(w3.z, t2.w, fmaf(w3.w, t3.w, bias.w))));
  float4 v;
  v.x = s.x / (1.f + __expf(-s.x));
  v.y = s.y / (1.f + __expf(-s.y));
  v.z = s.z / (1.f + __expf(-s.z));
  v.w = s.w / (1.f + __expf(-s.w));
  *(float4*)(xc + (size_t)bl * DI + d) = v;
  union { ushort_t u[4]; unsigned long long ll; } pk;
  pk.u[0] = f2bf(v.x); pk.u[1] = f2bf(v.y); pk.u[2] = f2bf(v.z); pk.u[3] = f2bf(v.w);
  *(unsigned long long*)(xcbf + (size_t)bl * DI + d) = pk.ll;
}

// ---- scan thread mapping: 512 threads; lane&31 + wave*32 = d, lane>>5 = n-half.
// State layout per (b,c): flat[ (nh*256 + d)*8 + j ]  (4096 floats, contiguous).
// ---------------- scan phase A: per-chunk summaries ----------------
__global__ __launch_bounds__(512) void scanA_kernel(const float* __restrict__ delta,
                                                    const float* __restrict__ xc,
                                                    const float* __restrict__ Bm,
                                                    const float* __restrict__ Alog,
                                                    float* __restrict__ Ap,
                                                    float* __restrict__ Bg) {
  __shared__ float Bs[CHUNK][DS];
  const int tid  = threadIdx.x;
  const int lane = tid & 63, wave = tid >> 6;
  const int d  = (wave << 5) | (lane & 31);
  const int nh = lane >> 5;
  const int n0 = nh * 8;
  const int b = blockIdx.x / NC, c = blockIdx.x % NC;
  const size_t rowbase = (size_t)b * L_ + (size_t)c * CHUNK;
  for (int i = tid; i < CHUNK * DS; i += 512) ((float*)Bs)[i] = Bm[rowbase * DS + i];
  float c0 = -__expf(Alog[d * DS]) * LOG2E;
  float aln[8];
  #pragma unroll
  for (int j = 0; j < 8; ++j) aln[j] = -__expf(Alog[d * DS + n0 + j]) * LOG2E;
  bool geom = true;
  #pragma unroll
  for (int j = 0; j < 8; ++j)
    geom = geom && (fabsf(aln[j] - (n0 + j + 1) * c0) <= 1e-3f * fabsf(aln[j]));
  float P[8], S[8];
  #pragma unroll
  for (int j = 0; j < 8; ++j) { P[j] = 1.f; S[j] = 0.f; }
  __syncthreads();
  for (int t0 = 0; t0 < CHUNK; t0 += 8) {
    float dl[8], xv[8];
    #pragma unroll
    for (int i = 0; i < 8; ++i) dl[i] = delta[(rowbase + t0 + i) * DI + d];
    #pragma unroll
    for (int i = 0; i < 8; ++i) xv[i] = xc[(rowbase + t0 + i) * DI + d];
    #pragma unroll
    for (int i = 0; i < 8; ++i) {
      float du = dl[i] * xv[i];
      if (geom) {
        float e1 = exp2f(dl[i] * c0);
        float a;
        if (nh) { float e2 = e1 * e1, e4 = e2 * e2; a = e4 * e4 * e1; }  // e1^9
        else a = e1;
        #pragma unroll
        for (int j = 0; j < 8; ++j) {
          P[j] *= a;
          S[j] = fmaf(a, S[j], du * Bs[t0 + i][n0 + j]);
          a *= e1;
        }
      } else {
        #pragma unroll
        for (int j = 0; j < 8; ++j) {
          float a = exp2f(dl[i] * aln[j]);
          P[j] *= a;
          S[j] = fmaf(a, S[j], du * Bs[t0 + i][n0 + j]);
        }
      }
    }
  }
  size_t ob = ((size_t)(b * NC + c) << 12) + ((nh * 256 + d) << 3);
  *(float4*)(Ap + ob)     = make_float4(P[0], P[1], P[2], P[3]);
  *(float4*)(Ap + ob + 4) = make_float4(P[4], P[5], P[6], P[7]);
  *(float4*)(Bg + ob)     = make_float4(S[0], S[1], S[2], S[3]);
  *(float4*)(Bg + ob + 4) = make_float4(S[4], S[5], S[6], S[7]);
}

// ---------------- scan phase B: scan over chunk summaries ----------------
__global__ __launch_bounds__(64) void scanB_kernel(const float* __restrict__ Ap,
                                                   const float* __restrict__ Bg,
                                                   float* __restrict__ sinit) {
  int g  = blockIdx.x * 64 + threadIdx.x;  // (b, state-slot)
  int b  = g >> 12;
  int dn = g & 4095;
  float s = 0.f;
  #pragma unroll 8
  for (int c = 0; c < NC; ++c) {
    size_t idx = ((size_t)(b * NC + c) << 12) + dn;
    sinit[idx] = s;
    s = fmaf(Ap[idx], s, Bg[idx]);
  }
}

// ---------------- scan phase C: replay with true init, emit y2 (bf16) -------
__global__ __launch_bounds__(512) void scanC_kernel(const float* __restrict__ delta,
                                                    const float* __restrict__ xc,
                                                    const float* __restrict__ Bm,
                                                    const float* __restrict__ Cm,
                                                    const float* __restrict__ Alog,
                                                    const float* __restrict__ Dp,
                                                    const float* __restrict__ xr,
                                                    const float* __restrict__ sinit,
                                                    ushort_t* __restrict__ y2bf) {
  __shared__ float Bs[CHUNK][DS];
  __shared__ float Cs[CHUNK][DS];
  const int tid  = threadIdx.x;
  const int lane = tid & 63, wave = tid >> 6;
  const int d  = (wave << 5) | (lane & 31);
  const int nh = lane >> 5;
  const int n0 = nh * 8;
  const int b = blockIdx.x / NC, c = blockIdx.x % NC;
  const size_t rowbase = (size_t)b * L_ + (size_t)c * CHUNK;
  for (int i = tid; i < CHUNK * DS; i += 512) {
    ((float*)Bs)[i] = Bm[rowbase * DS + i];
    ((float*)Cs)[i] = Cm[rowbase * DS + i];
  }
  float c0 = -__expf(Alog[d * DS]) * LOG2E;
  float aln[8];
  #pragma unroll
  for (int j = 0; j < 8; ++j) aln[j] = -__expf(Alog[d * DS + n0 + j]) * LOG2E;
  bool geom = true;
  #pragma unroll
  for (int j = 0; j < 8; ++j)
    geom = geom && (fabsf(aln[j] - (n0 + j + 1) * c0) <= 1e-3f * fabsf(aln[j]));
  const float Dd = Dp[d];
  float S[8];
  {
    size_t ib = ((size_t)(b * NC + c) << 12) + ((nh * 256 + d) << 3);
    float4 v0 = *(const float4*)(sinit + ib);
    float4 v1 = *(const float4*)(sinit + ib + 4);
    S[0] = v0.x; S[1] = v0.y; S[2] = v0.z; S[3] = v0.w;
    S[4] = v1.x; S[5] = v1.y; S[6] = v1.z; S[7] = v1.w;
  }
  __syncthreads();
  for (int t0 = 0; t0 < CHUNK; t0 += 8) {
    float dl[8], xv[8], rv[8];
    #pragma unroll
    for (int i = 0; i < 8; ++i) dl[i] = delta[(rowbase + t0 + i) * DI + d];
    #pragma unroll
    for (int i = 0; i < 8; ++i) xv[i] = xc[(rowbase + t0 + i) * DI + d];
    #pragma unroll
    for (int i = 0; i < 8; ++i) rv[i] = xr[(rowbase + t0 + i) * 512 + 256 + d];
    #pragma unroll
    for (int i = 0; i < 8; ++i) {
      float du = dl[i] * xv[i];
      float y = 0.f;
      if (geom) {
        float e1 = exp2f(dl[i] * c0);
        float a;
        if (nh) { float e2 = e1 * e1, e4 = e2 * e2; a = e4 * e4 * e1; }
        else a = e1;
        #pragma unroll
        for (int j = 0; j < 8; ++j) {
          S[j] = fmaf(a, S[j], du * Bs[t0 + i][n0 + j]);
          y = fmaf(S[j], Cs[t0 + i][n0 + j], y);
          a *= e1;
        }
      } else {
        #pragma unroll
        for (int j = 0; j < 8; ++j) {
          float a = exp2f(dl[i] * aln[j]);
          S[j] = fmaf(a, S[j], du * Bs[t0 + i][n0 + j]);
          y = fmaf(S[j], Cs[t0 + i][n0 + j], y);
        }
      }
      float yo = __shfl_xor(y, 32);
      if (nh == 0) {
        float yt = y + yo + xv[i] * Dd;
        float sil = rv[i] / (1.f + __expf(-rv[i]));
        y2bf[(rowbase + t0 + i) * DI + d] = f2bf(yt * sil);
      }
    }
  }
}

extern "C" void kernel_launch(void* const* d_in, const int* in_sizes, int n_in,
                              void* d_out, int out_size, void* d_ws, size_t ws_size,
                              hipStream_t stream) {
  const float* x      = (const float*)d_in[0];
  const float* norm_w = (const float*)d_in[1];
  const float* inW    = (const float*)d_in[2];
  const float* convw  = (const float*)d_in[3];
  const float* convb  = (const float*)d_in[4];
  const float* xprojw = (const float*)d_in[5];
  const float* dtw    = (const float*)d_in[6];
  const float* dtb    = (const float*)d_in[7];
  const float* alog   = (const float*)d_in[8];
  const float* Dp     = (const float*)d_in[9];
  const float* outw   = (const float*)d_in[10];
  float* out = (float*)d_out;

  const size_t CS = (size_t)B_ * NC * DI * DS;  // 2,097,152
  float* ws    = (float*)d_ws;
  float* xr    = ws;                        // M_*512 fp32
  float* xc    = xr + (size_t)M_ * 512;     // M_*256 fp32
  float* delta = xc + (size_t)M_ * DI;      // M_*256 fp32
  float* Bmv   = delta + (size_t)M_ * DI;   // M_*16
  float* Cmv   = Bmv + (size_t)M_ * DS;     // M_*16
  float* Ap    = Cmv + (size_t)M_ * DS;     // CS (later aliased as y2bf)
  float* Bg    = Ap + CS;                   // CS
  float* sinit = Bg + CS;                   // CS
  ushort_t* bfbase = (ushort_t*)(sinit + CS);
  ushort_t* xbf    = bfbase;                       // M_*128 (dead after G1)
  ushort_t* xcbf   = bfbase;                       // M_*256 (same region)
  ushort_t* inWt   = bfbase + (size_t)M_ * DI;     // 512*128
  ushort_t* WbigT  = inWt + 512 * 128;             // 288*256
  ushort_t* outWt  = WbigT + NB * DI;              // 128*256
  ushort_t* y2bf   = (ushort_t*)Ap;                // M_*256 (Ap dead after scanB)

  prep_rms_kernel<<<M_ / 4 + (PREP_N + 255) / 256, 256, 0, stream>>>(
      x, norm_w, inW, xprojw, dtw, outw, xbf, inWt, WbigT, outWt);
  gemm_mfma_kernel<64, 0><<<dim3(M_ / 128, 512 / 64), 256, 0, stream>>>(
      xbf, inWt, xr, DM, 512, nullptr, nullptr, nullptr, nullptr);
  conv_silu_kernel<<<(M_ * DI / 4) / 256, 256, 0, stream>>>(xr, convw, convb, xc, xcbf);
  gemm_mfma_kernel<32, 1><<<dim3(M_ / 128, NB / 32), 256, 0, stream>>>(
      xcbf, WbigT, delta, DI, DI, dtb, Bmv, Cmv, nullptr);
  scanA_kernel<<<B_ * NC, 512, 0, stream>>>(delta, xc, Bmv, alog, Ap, Bg);
  scanB_kernel<<<(B_ * DI * DS) / 64, 64, 0, stream>>>(Ap, Bg, sinit);
  scanC_kernel<<<B_ * NC, 512, 0, stream>>>(delta, xc, Bmv, Cmv, alog, Dp, xr, sinit, y2bf);
  gemm_mfma_kernel<32, 2><<<dim3(M_ / 128, DM / 32), 256, 0, stream>>>(
      y2bf, outWt, out, DI, DM, nullptr, nullptr, nullptr, x);
}

// Round 6
// 172.300 us; speedup vs baseline: 1.1169x; 1.1169x over previous
//
#include <hip/hip_runtime.h>
#include <math.h>

#define B_    4
#define L_    4096
#define DM    128
#define DI    256
#define DS    16
#define DTR   8
#define XPN   (DTR + 2*DS)   // 40
#define NB    (DI + 2*DS)    // 288 fused xproj output cols
#define M_    (B_*L_)        // 16384
#define CHUNK 32
#define NC    (L_/CHUNK)     // 128
#define LOG2E 1.4426950408889634f
#define PREP_N (512*128 + NB*DI + DM*DI)   // 172032

typedef __attribute__((ext_vector_type(8))) short bf16x8;   // 8 bf16 = 4 VGPR
typedef __attribute__((ext_vector_type(4))) float f32x4;    // MFMA acc
typedef unsigned short ushort_t;

__device__ __forceinline__ ushort_t f2bf(float f) {  // fp32 -> bf16 RNE
  unsigned int u = __float_as_uint(f);
  u += 0x7FFFu + ((u >> 16) & 1u);
  return (ushort_t)(u >> 16);
}
__device__ __forceinline__ float bf2f(ushort_t u) {
  return __uint_as_float(((unsigned int)u) << 16);
}

// ---------------- prep (weights->bf16 transposed, dtproj folded) + rmsnorm ----
__global__ __launch_bounds__(256) void prep_rms_kernel(const float* __restrict__ x,
                                                       const float* __restrict__ nw,
                                                       const float* __restrict__ inW,
                                                       const float* __restrict__ Wx,
                                                       const float* __restrict__ Wdt,
                                                       const float* __restrict__ outw,
                                                       ushort_t* __restrict__ xbf,
                                                       ushort_t* __restrict__ inWt,
                                                       ushort_t* __restrict__ WbigT,
                                                       ushort_t* __restrict__ outWt) {
  if (blockIdx.x < M_ / 4) {  // rmsnorm -> bf16
    int row  = blockIdx.x * 4 + (threadIdx.x >> 6);
    int lane = threadIdx.x & 63;
    const float* xp = x + (size_t)row * DM;
    float v0 = xp[lane], v1 = xp[lane + 64];
    float s = v0 * v0 + v1 * v1;
    #pragma unroll
    for (int off = 32; off > 0; off >>= 1) s += __shfl_xor(s, off);
    float r = rsqrtf(s / DM + 1e-5f);
    ushort_t* op = xbf + (size_t)row * DM;
    op[lane]      = f2bf(v0 * r * nw[lane]);
    op[lane + 64] = f2bf(v1 * r * nw[lane + 64]);
    return;
  }
  int g = (blockIdx.x - M_ / 4) * 256 + threadIdx.x;
  if (g < 512 * 128) {
    int n = g >> 7, k = g & 127;
    inWt[g] = f2bf(inW[k * 512 + n]);
  } else if (g < 512 * 128 + NB * DI) {
    int q = g - 512 * 128;
    int c = q >> 8, k = q & 255;
    float v;
    if (c < DI) {
      v = 0.f;
      #pragma unroll
      for (int j = 0; j < DTR; ++j) v = fmaf(Wx[k * XPN + j], Wdt[j * DI + c], v);
    } else {
      v = Wx[k * XPN + DTR + (c - DI)];
    }
    WbigT[q] = f2bf(v);
  } else if (g < PREP_N) {
    int q = g - (512 * 128 + NB * DI);
    int n = q >> 8, k = q & 255;
    outWt[q] = f2bf(outw[k * DM + n]);
  }
}

// ---------------- G1 fused: in_proj MFMA + depthwise conv + SiLU -------------
// A = xbf[M][128]. Col-tiles by<4 -> xi (conv+silu -> xcbf bf16);
// by>=4 -> res (-> resbf bf16). Boundary rows for conv via extra 16-row MFMA
// tile on wave 0 (A staged with 16 leading rows, zero at batch starts).
__global__ __launch_bounds__(256) void g1_conv_kernel(const ushort_t* __restrict__ A,
                                                      const ushort_t* __restrict__ Wt,
                                                      const float* __restrict__ cw,
                                                      const float* __restrict__ cb,
                                                      ushort_t* __restrict__ xcbf,
                                                      ushort_t* __restrict__ resbf) {
  constexpr int BM = 128, BN = 64, BK = 64, KK = 128, NT = BN / 16;
  __shared__ __align__(16) char smem_raw[35648];
  ushort_t (*Asm)[145][8] = (ushort_t (*)[145][8])smem_raw;          // 18560 B
  ushort_t (*Bsm)[65][8]  = (ushort_t (*)[65][8])(smem_raw + 18560); //  8320 B
  float* T = (float*)smem_raw;                                       // [131][68]
  const int tid  = threadIdx.x;
  const int wave = tid >> 6, lane = tid & 63;
  const int quad = lane >> 4, l16 = lane & 15;
  const int row0 = blockIdx.x * BM;
  const int by   = blockIdx.y;
  const int col0 = by * BN;
  const bool zpad = (row0 & (L_ - 1)) == 0;  // batch start: rows <row0 are 0
  f32x4 acc[2][NT], acc2[NT];
  #pragma unroll
  for (int mt = 0; mt < 2; ++mt)
    #pragma unroll
    for (int nt = 0; nt < NT; ++nt) acc[mt][nt] = (f32x4){0.f, 0.f, 0.f, 0.f};
  #pragma unroll
  for (int nt = 0; nt < NT; ++nt) acc2[nt] = (f32x4){0.f, 0.f, 0.f, 0.f};

  for (int k0 = 0; k0 < KK; k0 += BK) {
    #pragma unroll
    for (int i = 0; i < 5; ++i) {  // A: 144 rows x 64 bf16 = 1152 b128
      int q = tid + i * 256;
      if (i < 4 || tid < 128) {
        int m = q >> 3, kb = q & 7;
        bf16x8 v = {0, 0, 0, 0, 0, 0, 0, 0};
        if (!(zpad && m < 16))
          v = *(const bf16x8*)(A + (size_t)(row0 - 16 + m) * KK + k0 + kb * 8);
        *(bf16x8*)(&Asm[kb][m][0]) = v;
      }
    }
    #pragma unroll
    for (int i = 0; i < 2; ++i) {  // B: 64x64 bf16
      int q = tid + i * 256;
      int n = q >> 3, kb = q & 7;
      *(bf16x8*)(&Bsm[kb][n][0]) =
          *(const bf16x8*)(Wt + (size_t)(col0 + n) * KK + k0 + kb * 8);
    }
    __syncthreads();
    #pragma unroll
    for (int ks = 0; ks < 2; ++ks) {
      bf16x8 af[2], bfr[NT];
      #pragma unroll
      for (int mt = 0; mt < 2; ++mt)
        af[mt] = *(const bf16x8*)(&Asm[ks * 4 + quad][16 + wave * 32 + mt * 16 + l16][0]);
      #pragma unroll
      for (int nt = 0; nt < NT; ++nt)
        bfr[nt] = *(const bf16x8*)(&Bsm[ks * 4 + quad][nt * 16 + l16][0]);
      #pragma unroll
      for (int mt = 0; mt < 2; ++mt)
        #pragma unroll
        for (int nt = 0; nt < NT; ++nt)
          acc[mt][nt] = __builtin_amdgcn_mfma_f32_16x16x32_bf16(af[mt], bfr[nt],
                                                                acc[mt][nt], 0, 0, 0);
      if (by < 4 && wave == 0) {  // boundary tile rows row0-16..row0-1
        bf16x8 ab = *(const bf16x8*)(&Asm[ks * 4 + quad][l16][0]);
        #pragma unroll
        for (int nt = 0; nt < NT; ++nt)
          acc2[nt] = __builtin_amdgcn_mfma_f32_16x16x32_bf16(ab, bfr[nt],
                                                             acc2[nt], 0, 0, 0);
      }
    }
    __syncthreads();
  }

  if (by < 4) {
    // dump xi tile to LDS: T[3+local][c], boundary rows T[0..2]
    #pragma unroll
    for (int mt = 0; mt < 2; ++mt)
      #pragma unroll
      for (int nt = 0; nt < NT; ++nt)
        #pragma unroll
        for (int r = 0; r < 4; ++r)
          T[(3 + wave * 32 + mt * 16 + quad * 4 + r) * 68 + nt * 16 + l16] =
              acc[mt][nt][r];
    if (wave == 0 && quad == 3) {
      #pragma unroll
      for (int nt = 0; nt < NT; ++nt)
        #pragma unroll
        for (int r = 1; r < 4; ++r)  // rows 13,14,15 -> T[0..2]
          T[(r - 1) * 68 + nt * 16 + l16] = acc2[nt][r];
    }
    __syncthreads();
    // conv(4, causal) + silu along rows; thread: col c, rows strip of 32
    const int c   = tid & 63;
    const int R0  = (tid >> 6) * 32;
    const int dch = col0 + c;
    float4 w4   = *(const float4*)(cw + dch * 4);
    float bias  = cb[dch];
    float t0 = T[(R0 + 0) * 68 + c];
    float t1 = T[(R0 + 1) * 68 + c];
    float t2 = T[(R0 + 2) * 68 + c];
    for (int rr = 0; rr < 32; ++rr) {
      float t3 = T[(R0 + rr + 3) * 68 + c];
      float s = fmaf(w4.x, t0, fmaf(w4.y, t1, fmaf(w4.z, t2, fmaf(w4.w, t3, bias))));
      float v = s / (1.f + __expf(-s));
      xcbf[(size_t)(row0 + R0 + rr) * DI + dch] = f2bf(v);
      t0 = t1; t1 = t2; t2 = t3;
    }
  } else {
    const int cr = col0 - 256;
    #pragma unroll
    for (int mt = 0; mt < 2; ++mt)
      #pragma unroll
      for (int nt = 0; nt < NT; ++nt) {
        int col   = cr + nt * 16 + l16;
        int rbase = row0 + wave * 32 + mt * 16 + quad * 4;
        #pragma unroll
        for (int r = 0; r < 4; ++r)
          resbf[(size_t)(rbase + r) * DI + col] = f2bf(acc[mt][nt][r]);
      }
  }
}

// ---------------- bf16 MFMA GEMM (xproj / out_proj) -------------------------
// EPI 1: xproj epilogue (delta fp32 / Bm / Cm).  EPI 2: C = acc + X (fp32).
template <int BN, int EPI>
__global__ __launch_bounds__(256) void gemm_mfma_kernel(const ushort_t* __restrict__ A,
                                                        const ushort_t* __restrict__ Wt,
                                                        float* __restrict__ C, int K, int ldc,
                                                        const float* __restrict__ bdt,
                                                        float* __restrict__ Bm,
                                                        float* __restrict__ Cm,
                                                        const float* __restrict__ X) {
  constexpr int BM = 128, BK = 64, NT = BN / 16;
  __shared__ __align__(16) ushort_t Asm[BK / 8][BM + 1][8];
  __shared__ __align__(16) ushort_t Bsm[BK / 8][BN + 1][8];
  const int tid  = threadIdx.x;
  const int wave = tid >> 6, lane = tid & 63;
  const int quad = lane >> 4, l16 = lane & 15;
  const int row0 = blockIdx.x * BM;
  const int col0 = blockIdx.y * BN;
  f32x4 acc[2][NT];
  #pragma unroll
  for (int mt = 0; mt < 2; ++mt)
    #pragma unroll
    for (int nt = 0; nt < NT; ++nt) acc[mt][nt] = (f32x4){0.f, 0.f, 0.f, 0.f};

  for (int k0 = 0; k0 < K; k0 += BK) {
    #pragma unroll
    for (int i = 0; i < 4; ++i) {
      int q = tid + i * 256;
      int m = q >> 3, kb = q & 7;
      *(bf16x8*)(&Asm[kb][m][0]) =
          *(const bf16x8*)(A + (size_t)(row0 + m) * K + k0 + kb * 8);
    }
    #pragma unroll
    for (int i = 0; i < (BN * 8) / 256; ++i) {
      int q = tid + i * 256;
      int n = q >> 3, kb = q & 7;
      *(bf16x8*)(&Bsm[kb][n][0]) =
          *(const bf16x8*)(Wt + (size_t)(col0 + n) * K + k0 + kb * 8);
    }
    __syncthreads();
    #pragma unroll
    for (int ks = 0; ks < 2; ++ks) {
      bf16x8 af[2], bfr[NT];
      #pragma unroll
      for (int mt = 0; mt < 2; ++mt)
        af[mt] = *(const bf16x8*)(&Asm[ks * 4 + quad][wave * 32 + mt * 16 + l16][0]);
      #pragma unroll
      for (int nt = 0; nt < NT; ++nt)
        bfr[nt] = *(const bf16x8*)(&Bsm[ks * 4 + quad][nt * 16 + l16][0]);
      #pragma unroll
      for (int mt = 0; mt < 2; ++mt)
        #pragma unroll
        for (int nt = 0; nt < NT; ++nt)
          acc[mt][nt] = __builtin_amdgcn_mfma_f32_16x16x32_bf16(af[mt], bfr[nt],
                                                                acc[mt][nt], 0, 0, 0);
    }
    __syncthreads();
  }
  #pragma unroll
  for (int mt = 0; mt < 2; ++mt) {
    #pragma unroll
    for (int nt = 0; nt < NT; ++nt) {
      int col   = col0 + nt * 16 + l16;
      int rbase = row0 + wave * 32 + mt * 16 + quad * 4;
      if (EPI == 1) {
        if (col < DI) {
          float bb = bdt[col];
          #pragma unroll
          for (int r = 0; r < 4; ++r) {
            float v = acc[mt][nt][r] + bb;
            C[(size_t)(rbase + r) * DI + col] = (v > 20.f) ? v : log1pf(__expf(v));
          }
        } else if (col < DI + DS) {
          #pragma unroll
          for (int r = 0; r < 4; ++r)
            Bm[(size_t)(rbase + r) * DS + (col - DI)] = acc[mt][nt][r];
        } else {
          #pragma unroll
          for (int r = 0; r < 4; ++r)
            Cm[(size_t)(rbase + r) * DS + (col - DI - DS)] = acc[mt][nt][r];
        }
      } else {
        #pragma unroll
        for (int r = 0; r < 4; ++r)
          C[(size_t)(rbase + r) * ldc + col] =
              acc[mt][nt][r] + X[(size_t)(rbase + r) * ldc + col];
      }
    }
  }
}

// ---- scan thread mapping: 512 threads; d = wave*32 + (lane&31), nh = lane>>5.
// ---------------- scan phase A: per-chunk summaries ----------------
__global__ __launch_bounds__(512) void scanA_kernel(const float* __restrict__ delta,
                                                    const ushort_t* __restrict__ xcbf,
                                                    const float* __restrict__ Bm,
                                                    const float* __restrict__ Alog,
                                                    float* __restrict__ Ap,
                                                    float* __restrict__ Bg) {
  __shared__ float Bs[CHUNK][DS];
  const int tid  = threadIdx.x;
  const int lane = tid & 63, wave = tid >> 6;
  const int d  = (wave << 5) | (lane & 31);
  const int nh = lane >> 5;
  const int n0 = nh * 8;
  const int b = blockIdx.x / NC, c = blockIdx.x % NC;
  const size_t rowbase = (size_t)b * L_ + (size_t)c * CHUNK;
  for (int i = tid; i < CHUNK * DS; i += 512) ((float*)Bs)[i] = Bm[rowbase * DS + i];
  float c0 = -__expf(Alog[d * DS]) * LOG2E;
  float aln[8];
  #pragma unroll
  for (int j = 0; j < 8; ++j) aln[j] = -__expf(Alog[d * DS + n0 + j]) * LOG2E;
  bool geom = true;
  #pragma unroll
  for (int j = 0; j < 8; ++j)
    geom = geom && (fabsf(aln[j] - (n0 + j + 1) * c0) <= 1e-3f * fabsf(aln[j]));
  float P[8], S[8];
  #pragma unroll
  for (int j = 0; j < 8; ++j) { P[j] = 1.f; S[j] = 0.f; }
  __syncthreads();
  for (int t0 = 0; t0 < CHUNK; t0 += 8) {
    float dl[8], xv[8];
    #pragma unroll
    for (int i = 0; i < 8; ++i) dl[i] = delta[(rowbase + t0 + i) * DI + d];
    #pragma unroll
    for (int i = 0; i < 8; ++i) xv[i] = bf2f(xcbf[(rowbase + t0 + i) * DI + d]);
    #pragma unroll
    for (int i = 0; i < 8; ++i) {
      float du = dl[i] * xv[i];
      if (geom) {
        float e1 = exp2f(dl[i] * c0);
        float a;
        if (nh) { float e2 = e1 * e1, e4 = e2 * e2; a = e4 * e4 * e1; }  // e1^9
        else a = e1;
        #pragma unroll
        for (int j = 0; j < 8; ++j) {
          P[j] *= a;
          S[j] = fmaf(a, S[j], du * Bs[t0 + i][n0 + j]);
          a *= e1;
        }
      } else {
        #pragma unroll
        for (int j = 0; j < 8; ++j) {
          float a = exp2f(dl[i] * aln[j]);
          P[j] *= a;
          S[j] = fmaf(a, S[j], du * Bs[t0 + i][n0 + j]);
        }
      }
    }
  }
  size_t ob = ((size_t)(b * NC + c) << 12) + ((nh * 256 + d) << 3);
  *(float4*)(Ap + ob)     = make_float4(P[0], P[1], P[2], P[3]);
  *(float4*)(Ap + ob + 4) = make_float4(P[4], P[5], P[6], P[7]);
  *(float4*)(Bg + ob)     = make_float4(S[0], S[1], S[2], S[3]);
  *(float4*)(Bg + ob + 4) = make_float4(S[4], S[5], S[6], S[7]);
}

// ---------------- scan phase B: scan over chunk summaries ----------------
__global__ __launch_bounds__(64) void scanB_kernel(const float* __restrict__ Ap,
                                                   const float* __restrict__ Bg,
                                                   float* __restrict__ sinit) {
  int g  = blockIdx.x * 64 + threadIdx.x;
  int b  = g >> 12;
  int dn = g & 4095;
  float s = 0.f;
  #pragma unroll 8
  for (int c = 0; c < NC; ++c) {
    size_t idx = ((size_t)(b * NC + c) << 12) + dn;
    sinit[idx] = s;
    s = fmaf(Ap[idx], s, Bg[idx]);
  }
}

// ---------------- scan phase C: replay with true init, emit y2 (bf16) -------
__global__ __launch_bounds__(512) void scanC_kernel(const float* __restrict__ delta,
                                                    const ushort_t* __restrict__ xcbf,
                                                    const float* __restrict__ Bm,
                                                    const float* __restrict__ Cm,
                                                    const float* __restrict__ Alog,
                                                    const float* __restrict__ Dp,
                                                    const ushort_t* __restrict__ resbf,
                                                    const float* __restrict__ sinit,
                                                    ushort_t* __restrict__ y2bf) {
  __shared__ float Bs[CHUNK][DS];
  __shared__ float Cs[CHUNK][DS];
  const int tid  = threadIdx.x;
  const int lane = tid & 63, wave = tid >> 6;
  const int d  = (wave << 5) | (lane & 31);
  const int nh = lane >> 5;
  const int n0 = nh * 8;
  const int b = blockIdx.x / NC, c = blockIdx.x % NC;
  const size_t rowbase = (size_t)b * L_ + (size_t)c * CHUNK;
  for (int i = tid; i < CHUNK * DS; i += 512) {
    ((float*)Bs)[i] = Bm[rowbase * DS + i];
    ((float*)Cs)[i] = Cm[rowbase * DS + i];
  }
  float c0 = -__expf(Alog[d * DS]) * LOG2E;
  float aln[8];
  #pragma unroll
  for (int j = 0; j < 8; ++j) aln[j] = -__expf(Alog[d * DS + n0 + j]) * LOG2E;
  bool geom = true;
  #pragma unroll
  for (int j = 0; j < 8; ++j)
    geom = geom && (fabsf(aln[j] - (n0 + j + 1) * c0) <= 1e-3f * fabsf(aln[j]));
  const float Dd = Dp[d];
  float S[8];
  {
    size_t ib = ((size_t)(b * NC + c) << 12) + ((nh * 256 + d) << 3);
    float4 v0 = *(const float4*)(sinit + ib);
    float4 v1 = *(const float4*)(sinit + ib + 4);
    S[0] = v0.x; S[1] = v0.y; S[2] = v0.z; S[3] = v0.w;
    S[4] = v1.x; S[5] = v1.y; S[6] = v1.z; S[7] = v1.w;
  }
  __syncthreads();
  for (int t0 = 0; t0 < CHUNK; t0 += 8) {
    float dl[8], xv[8], rv[8];
    #pragma unroll
    for (int i = 0; i < 8; ++i) dl[i] = delta[(rowbase + t0 + i) * DI + d];
    #pragma unroll
    for (int i = 0; i < 8; ++i) xv[i] = bf2f(xcbf[(rowbase + t0 + i) * DI + d]);
    #pragma unroll
    for (int i = 0; i < 8; ++i) rv[i] = bf2f(resbf[(rowbase + t0 + i) * DI + d]);
    #pragma unroll
    for (int i = 0; i < 8; ++i) {
      float du = dl[i] * xv[i];
      float y = 0.f;
      if (geom) {
        float e1 = exp2f(dl[i] * c0);
        float a;
        if (nh) { float e2 = e1 * e1, e4 = e2 * e2; a = e4 * e4 * e1; }
        else a = e1;
        #pragma unroll
        for (int j = 0; j < 8; ++j) {
          S[j] = fmaf(a, S[j], du * Bs[t0 + i][n0 + j]);
          y = fmaf(S[j], Cs[t0 + i][n0 + j], y);
          a *= e1;
        }
      } else {
        #pragma unroll
        for (int j = 0; j < 8; ++j) {
          float a = exp2f(dl[i] * aln[j]);
          S[j] = fmaf(a, S[j], du * Bs[t0 + i][n0 + j]);
          y = fmaf(S[j], Cs[t0 + i][n0 + j], y);
        }
      }
      float yo = __shfl_xor(y, 32);
      if (nh == 0) {
        float yt = y + yo + xv[i] * Dd;
        float sil = rv[i] / (1.f + __expf(-rv[i]));
        y2bf[(rowbase + t0 + i) * DI + d] = f2bf(yt * sil);
      }
    }
  }
}

extern "C" void kernel_launch(void* const* d_in, const int* in_sizes, int n_in,
                              void* d_out, int out_size, void* d_ws, size_t ws_size,
                              hipStream_t stream) {
  const float* x      = (const float*)d_in[0];
  const float* norm_w = (const float*)d_in[1];
  const float* inW    = (const float*)d_in[2];
  const float* convw  = (const float*)d_in[3];
  const float* convb  = (const float*)d_in[4];
  const float* xprojw = (const float*)d_in[5];
  const float* dtw    = (const float*)d_in[6];
  const float* dtb    = (const float*)d_in[7];
  const float* alog   = (const float*)d_in[8];
  const float* Dp     = (const float*)d_in[9];
  const float* outw   = (const float*)d_in[10];
  float* out = (float*)d_out;

  const size_t CS = (size_t)B_ * NC * DI * DS;  // 2,097,152
  float* ws    = (float*)d_ws;
  float* delta = ws;                        // M_*256 fp32
  float* Bmv   = delta + (size_t)M_ * DI;   // M_*16
  float* Cmv   = Bmv + (size_t)M_ * DS;     // M_*16
  float* Ap    = Cmv + (size_t)M_ * DS;     // CS (later aliased as y2bf)
  float* Bg    = Ap + CS;                   // CS
  float* sinit = Bg + CS;                   // CS
  ushort_t* bfbase = (ushort_t*)(sinit + CS);
  ushort_t* xbf    = bfbase;                       // M_*128 (live through G1)
  ushort_t* xcbf   = xbf + (size_t)M_ * DM;        // M_*256
  ushort_t* resbf  = xcbf + (size_t)M_ * DI;       // M_*256
  ushort_t* inWt   = resbf + (size_t)M_ * DI;      // 512*128
  ushort_t* WbigT  = inWt + 512 * 128;             // 288*256
  ushort_t* outWt  = WbigT + NB * DI;              // 128*256
  ushort_t* y2bf   = (ushort_t*)Ap;                // M_*256 (Ap dead after scanB)

  prep_rms_kernel<<<M_ / 4 + (PREP_N + 255) / 256, 256, 0, stream>>>(
      x, norm_w, inW, xprojw, dtw, outw, xbf, inWt, WbigT, outWt);
  g1_conv_kernel<<<dim3(M_ / 128, 8), 256, 0, stream>>>(
      xbf, inWt, convw, convb, xcbf, resbf);
  gemm_mfma_kernel<32, 1><<<dim3(M_ / 128, NB / 32), 256, 0, stream>>>(
      xcbf, WbigT, delta, DI, DI, dtb, Bmv, Cmv, nullptr);
  scanA_kernel<<<B_ * NC, 512, 0, stream>>>(delta, xcbf, Bmv, alog, Ap, Bg);
  scanB_kernel<<<(B_ * DI * DS) / 64, 64, 0, stream>>>(Ap, Bg, sinit);
  scanC_kernel<<<B_ * NC, 512, 0, stream>>>(delta, xcbf, Bmv, Cmv, alog, Dp,
                                            resbf, sinit, y2bf);
  gemm_mfma_kernel<32, 2><<<dim3(M_ / 128, DM / 32), 256, 0, stream>>>(
      y2bf, outWt, out, DI, DM, nullptr, nullptr, nullptr, x);
}